// Round 4
// baseline (397.589 us; speedup 1.0000x reference)
//
#include <hip/hip_runtime.h>
#include <math.h>

// B=16 P=16 I=16 L=64 D=128 F=128 C=1024
#define Bb 16
#define Pp 16
#define Ii 16
#define Ll 64
#define Dd 128
#define Ff 128
#define Cc 1024

static __device__ __forceinline__ float dot4(float4 a, float4 b) {
    return a.x*b.x + a.y*b.y + a.z*b.z + a.w*b.w;
}

// ---------------- Kernel 1: fused front end -------------------------------
// 3072 blocks, interleaved by blk%3:
//   blk%3==0 (1024 blocks): masked mean over L + conv — ONE WAVE PER bpi,
//     zero __syncthreads, reads only len rows (no clamp). R1-R3 showed
//     wave-level MLP is not the constraint; per-CU load duty cycle is.
//     Wave-autonomous structure keeps every wave in its load loop at full
//     duty and cuts path_emb logical traffic 134->68 MB.
//   else (2048 blocks): candidate dot scores (batch-4 in-flight loads).
// dots block 0 zeroes sumexp (consumed by k_exp_sum).
__global__ __launch_bounds__(256, 8) void k_front(
    const float* __restrict__ path_emb, const int* __restrict__ path_len,
    const float* __restrict__ conv_w, const float* __restrict__ conv_b,
    const float* __restrict__ cand_emb, const float* __restrict__ score_w,
    float* __restrict__ inst, float* __restrict__ dots,
    float* __restrict__ sumexp)
{
    int blk = blockIdx.x;
    int t = threadIdx.x;
    if (blk % 3 == 0) {
        // ---- masked mean + conv: one wave handles one bpi ----
        __shared__ float4 meanv[4][32];   // per-wave mean broadcast slice
        int w = t >> 6;                   // wave id 0..3
        int lane = t & 63;
        int bpi = (blk / 3) * 4 + w;
        int len = path_len[bpi];
        const float4* base = (const float4*)(path_emb + (size_t)bpi * Ll * Dd);
        int quad = lane & 31;             // float4 column 0..31
        int rg = lane >> 5;               // row parity 0/1

        // full-duty streamed loads: each iteration = one coalesced 1KB
        // wave-load of rows l (lanes 0-31) and l+1 (lanes 32-63)
        float4 acc = make_float4(0.f, 0.f, 0.f, 0.f);
        for (int l = rg; l < len; l += 2) {
            float4 v = base[l * 32 + quad];
            acc.x += v.x; acc.y += v.y; acc.z += v.z; acc.w += v.w;
        }
        // combine even/odd row partial sums across the two half-waves
        acc.x += __shfl_xor(acc.x, 32);
        acc.y += __shfl_xor(acc.y, 32);
        acc.z += __shfl_xor(acc.z, 32);
        acc.w += __shfl_xor(acc.w, 32);
        float inv = 1.0f / (float)len;
        acc.x *= inv; acc.y *= inv; acc.z *= inv; acc.w *= inv;
        if (lane < 32) meanv[w][quad] = acc;
        // wave-coherent LDS: same-wave write->read, compiler emits lgkmcnt

        // conv projection: lane computes outputs f=lane and f=lane+64
        const float4* w0 = (const float4*)(conv_w) + (size_t)lane * 32;
        const float4* w1 = (const float4*)(conv_w) + (size_t)(lane + 64) * 32;
        float a0 = conv_b[lane];
        float a1 = conv_b[lane + 64];
#pragma unroll 4
        for (int dq = 0; dq < 32; ++dq) {
            float4 m = meanv[w][dq];      // broadcast read
            a0 += dot4(m, w0[dq]);
            a1 += dot4(m, w1[dq]);
        }
        inst[(size_t)bpi * Ff + lane]      = a0;
        inst[(size_t)bpi * Ff + lane + 64] = a1;
    } else {
        // ---- candidate dot scores ----
        int blk2 = blk - blk / 3 - 1;     // 0..2047
        if (blk2 == 0 && t < Bb) sumexp[t] = 0.f;
        int chunk = blk2 & 7;
        int bp = blk2 >> 3;
        int quad = t & 31, cl = t >> 5;   // 8 candidates concurrently
        float4 swq = ((const float4*)(score_w + 384))[quad];
        const float4* cbase = (const float4*)(cand_emb + ((size_t)bp * Cc + chunk * 128) * Dd);

        // four batches of 4 in-flight loads each (fits 64-VGPR budget)
#pragma unroll
        for (int h = 0; h < 4; ++h) {
            float4 w0 = cbase[(size_t)(cl + 32 * h + 0 ) * 32 + quad];
            float4 w1 = cbase[(size_t)(cl + 32 * h + 8 ) * 32 + quad];
            float4 w2 = cbase[(size_t)(cl + 32 * h + 16) * 32 + quad];
            float4 w3 = cbase[(size_t)(cl + 32 * h + 24) * 32 + quad];
            __builtin_amdgcn_sched_barrier(0);   // keep the 4 loads batched

            float part[4];
            part[0] = dot4(w0, swq);
            part[1] = dot4(w1, swq);
            part[2] = dot4(w2, swq);
            part[3] = dot4(w3, swq);
#pragma unroll
            for (int u = 0; u < 4; ++u) {
                float p = part[u];
                p += __shfl_xor(p, 16);
                p += __shfl_xor(p, 8);
                p += __shfl_xor(p, 4);
                p += __shfl_xor(p, 2);
                p += __shfl_xor(p, 1);
                part[u] = p;
            }
            if (quad == 0) {
#pragma unroll
                for (int u = 0; u < 4; ++u)
                    dots[(size_t)bp * Cc + chunk * 128 + cl + 32 * h + 8 * u] = part[u];
            }
        }
    }
}

// ---------------- Generic tiled GEMM: C[M,N] = A[M,128] @ W[N,128]^T + b --
// Mtile=64, Ntile=96, 256 threads, micro-tile 4x6 per thread.
__global__ __launch_bounds__(256) void k_gemm(
    const float* __restrict__ A, const float* __restrict__ W,
    const float* __restrict__ bias, float* __restrict__ C,
    int N, int nbn)
{
    __shared__ float4 As[32 * 65];
    __shared__ float4 Wsh[32 * 97];
    int t = threadIdx.x;
    int bm = blockIdx.x / nbn, bn = blockIdx.x % nbn;

    {
        const float4* Ag = (const float4*)A + (size_t)(bm * 64) * 32;
        int k4 = t & 31;
        int m0 = (t >> 5) * 8;
#pragma unroll
        for (int r = 0; r < 8; ++r)
            As[k4 * 65 + m0 + r] = Ag[(size_t)(m0 + r) * 32 + k4];
    }
    {
        const float4* Wg = (const float4*)W + (size_t)(bn * 96) * 32;
        int k4 = t & 31;
        int n0 = (t >> 5) * 12;
#pragma unroll
        for (int r = 0; r < 12; ++r)
            Wsh[k4 * 97 + n0 + r] = Wg[(size_t)(n0 + r) * 32 + k4];
    }
    __syncthreads();

    int tn = t & 15;   // lane-fast over n -> coalesced C stores
    int tm = t >> 4;
    float acc[4][6];
#pragma unroll
    for (int i = 0; i < 4; ++i)
#pragma unroll
        for (int j = 0; j < 6; ++j) acc[i][j] = 0.f;

#pragma unroll 2
    for (int k4 = 0; k4 < 32; ++k4) {
        float4 a[4], b[6];
#pragma unroll
        for (int i = 0; i < 4; ++i) a[i] = As[k4 * 65 + tm + 16 * i];
#pragma unroll
        for (int j = 0; j < 6; ++j) b[j] = Wsh[k4 * 97 + tn + 16 * j];
#pragma unroll
        for (int i = 0; i < 4; ++i)
#pragma unroll
            for (int j = 0; j < 6; ++j)
                acc[i][j] += dot4(a[i], b[j]);
    }

#pragma unroll
    for (int i = 0; i < 4; ++i) {
        int m = bm * 64 + tm + 16 * i;
#pragma unroll
        for (int j = 0; j < 6; ++j) {
            int n = bn * 96 + tn + 16 * j;
            C[(size_t)m * N + n] = acc[i][j] + bias[n];
        }
    }
}

// ---------------- Kernel 2b: pia attention + mean + out proj -> meta -----
// grid = B*P = 256 blocks, 256 threads. out_w staged in LDS (f4-transposed).
__global__ __launch_bounds__(256) void k_pia_post(
    const float* __restrict__ qkv,
    const float* __restrict__ out_w, const float* __restrict__ out_b,
    float* __restrict__ meta)
{
    __shared__ float4 qs[16 * 33];
    __shared__ float4 ks[16 * 33];
    __shared__ float4 vs[16 * 33];
    __shared__ float4 ows[32 * 132];   // [k4][f] f4-transposed out_w
    __shared__ float Ss[16 * 17];
    __shared__ float wj[16];
    __shared__ float4 z4[32];
    int t = threadIdx.x, bp = blockIdx.x;
    float* vsf = (float*)vs;

    const float4* src = (const float4*)(qkv + (size_t)bp * 6144);
    for (int idx = t; idx < 1536; idx += 256) {
        int i = idx / 96, q = idx - i * 96;
        float4 v = src[idx];
        if (q < 32)       qs[i * 33 + q]        = v;
        else if (q < 64)  ks[i * 33 + (q - 32)] = v;
        else              vs[i * 33 + (q - 64)] = v;
    }
    {
        const float4* owg = (const float4*)out_w;
#pragma unroll
        for (int r = 0; r < 16; ++r) {
            int idx = t + 256 * r;
            int f = idx >> 5, k4 = idx & 31;
            ows[k4 * 132 + f] = owg[idx];
        }
    }
    __syncthreads();

    {
        int si = t >> 4, sj = t & 15;
        float s = 0.f;
#pragma unroll 8
        for (int dq = 0; dq < 32; ++dq)
            s += dot4(qs[si * 33 + dq], ks[sj * 33 + dq]);
        Ss[si * 17 + sj] = s * 0.08838834764831843f;
    }
    __syncthreads();
    if (t < 16) {
        float mx = -1e30f;
        for (int j = 0; j < 16; ++j) mx = fmaxf(mx, Ss[t * 17 + j]);
        float e[16]; float sum = 0.f;
        for (int j = 0; j < 16; ++j) { e[j] = expf(Ss[t * 17 + j] - mx); sum += e[j]; }
        float inv = 1.0f / sum;
        for (int j = 0; j < 16; ++j) Ss[t * 17 + j] = e[j] * inv;
    }
    __syncthreads();
    if (t < 16) {
        float s = 0.f;
        for (int i2 = 0; i2 < 16; ++i2) s += Ss[i2 * 17 + t];
        wj[t] = s * (1.0f / 16.0f);
    }
    __syncthreads();
    if (t < 128) {
        float s = 0.f;
#pragma unroll
        for (int j = 0; j < 16; ++j) s += wj[j] * vsf[j * 132 + t];
        ((float*)z4)[t] = s;
    }
    __syncthreads();
    if (t < 128) {
        float a = out_b[t];
#pragma unroll 8
        for (int k4 = 0; k4 < 32; ++k4) a += dot4(z4[k4], ows[k4 * 132 + t]);
        meta[(size_t)bp * Ff + t] = a;
    }
}

// ---------------- Kernel 3b: mpa attention + qia + base, per b ----------
__global__ __launch_bounds__(256) void k_mpa_post(
    const float* __restrict__ qkv, const float* __restrict__ meta,
    const float* __restrict__ query,
    const float* __restrict__ out_w, const float* __restrict__ out_b,
    const float* __restrict__ qia_in_w, const float* __restrict__ qia_in_b,
    const float* __restrict__ qia_out_w, const float* __restrict__ qia_out_b,
    const float* __restrict__ score_w, const float* __restrict__ score_b,
    float* __restrict__ basev)
{
    __shared__ float4 qs[16 * 33];
    __shared__ float4 ks[16 * 33];
    __shared__ float4 vs[16 * 33];
    __shared__ float Ss[16 * 17];
    __shared__ float wj[16];
    __shared__ float4 z4[32];
    __shared__ float4 mm4[32];
    __shared__ float v1s[128];
    __shared__ float4 tq4[32];
    __shared__ float v2s[128];
    __shared__ float red[128];
    int t = threadIdx.x, b = blockIdx.x;
    float* vsf = (float*)vs;

    const float4* src = (const float4*)(qkv + (size_t)b * 6144);
    for (int idx = t; idx < 1536; idx += 256) {
        int i = idx / 96, q = idx - i * 96;
        float4 v = src[idx];
        if (q < 32)       qs[i * 33 + q]        = v;
        else if (q < 64)  ks[i * 33 + (q - 32)] = v;
        else              vs[i * 33 + (q - 64)] = v;
    }
    float mmacc = 0.f;
    if (t < 128) {
#pragma unroll
        for (int p = 0; p < 16; ++p) mmacc += meta[(size_t)b * 2048 + p * 128 + t];
        mmacc *= (1.0f / 16.0f);
    }
    __syncthreads();

    {
        int si = t >> 4, sj = t & 15;
        float s = 0.f;
#pragma unroll 8
        for (int dq = 0; dq < 32; ++dq)
            s += dot4(qs[si * 33 + dq], ks[sj * 33 + dq]);
        Ss[si * 17 + sj] = s * 0.08838834764831843f;
    }
    if (t < 128) ((float*)mm4)[t] = mmacc;
    __syncthreads();
    if (t < 16) {
        float mx = -1e30f;
        for (int j = 0; j < 16; ++j) mx = fmaxf(mx, Ss[t * 17 + j]);
        float e[16]; float sum = 0.f;
        for (int j = 0; j < 16; ++j) { e[j] = expf(Ss[t * 17 + j] - mx); sum += e[j]; }
        float inv = 1.0f / sum;
        for (int j = 0; j < 16; ++j) Ss[t * 17 + j] = e[j] * inv;
    }
    __syncthreads();
    if (t < 16) {
        float s = 0.f;
        for (int i2 = 0; i2 < 16; ++i2) s += Ss[i2 * 17 + t];
        wj[t] = s * (1.0f / 16.0f);
    }
    __syncthreads();
    if (t < 128) {
        float s = 0.f;
#pragma unroll
        for (int j = 0; j < 16; ++j) s += wj[j] * vsf[j * 132 + t];
        ((float*)z4)[t] = s;
    }
    __syncthreads();

    if (t < 128) {
        const float4* w = (const float4*)(out_w) + (size_t)t * 32;
        float a = out_b[t];
#pragma unroll 8
        for (int dq = 0; dq < 32; ++dq) a += dot4(z4[dq], w[dq]);
        v1s[t] = a;
    } else {
        int f = t - 128;
        const float4* w = (const float4*)(qia_in_w) + (size_t)(256 + f) * 32;
        float a = qia_in_b[256 + f];
#pragma unroll 8
        for (int dq = 0; dq < 32; ++dq) a += dot4(mm4[dq], w[dq]);
        ((float*)tq4)[f] = a;
    }
    __syncthreads();
    if (t < 128) {
        const float4* w = (const float4*)(qia_out_w) + (size_t)t * 32;
        float a = qia_out_b[t];
#pragma unroll 8
        for (int dq = 0; dq < 32; ++dq) a += dot4(tq4[dq], w[dq]);
        v2s[t] = a;
    }
    __syncthreads();
    if (t < 128) {
        red[t] = query[(size_t)b * Dd + t] * score_w[t]
               + v1s[t] * score_w[128 + t]
               + v2s[t] * score_w[256 + t];
    }
    __syncthreads();
    for (int s = 64; s > 0; s >>= 1) {
        if (t < s) red[t] += red[t + s];
        __syncthreads();
    }
    if (t == 0) basev[b] = red[0] + score_b[0];
}

// ---------------- Kernel 4: exp(dot+base) with mask, per-b sum -----------
// grid = B*4 = 64 blocks, 256 threads; each block handles 4096 scores
// (4 consecutive p's of one b) as 1024 float4.
__global__ __launch_bounds__(256) void k_exp_sum(
    const float* __restrict__ dots, const int* __restrict__ cand_len,
    const float* __restrict__ basev, float* __restrict__ eout,
    float* __restrict__ sumexp)
{
    int blk = blockIdx.x;
    int b = blk >> 2, q = blk & 3;
    int t = threadIdx.x;
    float bb = basev[b];
    size_t off = (size_t)b * 16384 + (size_t)q * 4096;
    const float4* d4 = (const float4*)(dots + off);
    float4* o4 = (float4*)(eout + off);
    float lsum = 0.f;
#pragma unroll
    for (int r = 0; r < 4; ++r) {
        int idx4 = t + 256 * r;            // 0..1023
        int p = q * 4 + (idx4 >> 8);       // global p within b
        int c0 = (idx4 & 255) * 4;         // candidate index of .x
        int clen = cand_len[b * Pp + p];
        float4 v = d4[idx4];
        float4 e;
        e.x = (c0 + 0 < clen) ? expf(v.x + bb) : 0.f;
        e.y = (c0 + 1 < clen) ? expf(v.y + bb) : 0.f;
        e.z = (c0 + 2 < clen) ? expf(v.z + bb) : 0.f;
        e.w = (c0 + 3 < clen) ? expf(v.w + bb) : 0.f;
        o4[idx4] = e;
        lsum += e.x + e.y + e.z + e.w;
    }
    __shared__ float red[256];
    red[t] = lsum;
    __syncthreads();
    for (int s = 128; s > 0; s >>= 1) {
        if (t < s) red[t] += red[t + s];
        __syncthreads();
    }
    if (t == 0) atomicAdd(&sumexp[b], red[0]);
}

// ---------------- Kernel 5: normalize ------------------------------------
__global__ __launch_bounds__(256) void k_norm(
    float* __restrict__ out, const float* __restrict__ sumexp)
{
    int idx = blockIdx.x * 256 + threadIdx.x;
    int b = idx >> 12;  // 4096 float4 per batch
    float inv = 1.0f / sumexp[b];
    float4* o4 = (float4*)out;
    float4 v = o4[idx];
    v.x *= inv; v.y *= inv; v.z *= inv; v.w *= inv;
    o4[idx] = v;
}

extern "C" void kernel_launch(void* const* d_in, const int* in_sizes, int n_in,
                              void* d_out, int out_size, void* d_ws, size_t ws_size,
                              hipStream_t stream)
{
    const float* query    = (const float*)d_in[0];
    const float* path_emb = (const float*)d_in[1];
    const int*   path_len = (const int*)  d_in[2];
    const float* cand_emb = (const float*)d_in[3];
    const int*   cand_len = (const int*)  d_in[4];
    const float* conv_w   = (const float*)d_in[5];
    const float* conv_b   = (const float*)d_in[6];
    const float* pia_in_w = (const float*)d_in[7];
    const float* pia_in_b = (const float*)d_in[8];
    const float* pia_out_w= (const float*)d_in[9];
    const float* pia_out_b= (const float*)d_in[10];
    const float* mpa_in_w = (const float*)d_in[11];
    const float* mpa_in_b = (const float*)d_in[12];
    const float* mpa_out_w= (const float*)d_in[13];
    const float* mpa_out_b= (const float*)d_in[14];
    const float* qia_in_w = (const float*)d_in[15];
    const float* qia_in_b = (const float*)d_in[16];
    const float* qia_out_w= (const float*)d_in[17];
    const float* qia_out_b= (const float*)d_in[18];
    const float* score_w  = (const float*)d_in[19];
    const float* score_b  = (const float*)d_in[20];
    float* out = (float*)d_out;

    float* ws      = (float*)d_ws;
    float* inst    = ws;                        // B*P*I*F = 524288 floats
    float* meta    = ws + 524288;               // B*P*F   = 32768
    float* basev   = ws + 524288 + 32768;       // 16
    float* sumexp  = basev + 16;                // 16
    float* qkv_pia = sumexp + 16;               // 4096*384 = 1572864
    float* qkv_mpa = qkv_pia + 1572864;         // 256*384  = 98304
    float* dots    = qkv_mpa + 98304;           // B*P*C    = 262144

    // 1) fused: masked-mean+conv (1024 blocks, 1 wave/bpi) + cand dots
    //    (2048 blocks), interleaved by blk%3
    k_front<<<3072, 256, 0, stream>>>(path_emb, path_len, conv_w, conv_b,
                                      cand_emb, score_w,
                                      inst, dots, sumexp);
    // 2) pia qkv: M=4096, N=384 -> 64 x 4 = 256 blocks
    k_gemm<<<64 * 4, 256, 0, stream>>>(inst, pia_in_w, pia_in_b, qkv_pia, 384, 4);
    // 3) pia attention + mean + out-proj
    k_pia_post<<<Bb * Pp, 256, 0, stream>>>(qkv_pia, pia_out_w, pia_out_b, meta);
    // 4) mpa qkv: M=256, N=384 -> 4 x 4 = 16 blocks
    k_gemm<<<4 * 4, 256, 0, stream>>>(meta, mpa_in_w, mpa_in_b, qkv_mpa, 384, 4);
    // 5) mpa attention + qia + per-b base scalar
    k_mpa_post<<<Bb, 256, 0, stream>>>(qkv_mpa, meta, query,
                                       mpa_out_w, mpa_out_b,
                                       qia_in_w, qia_in_b, qia_out_w, qia_out_b,
                                       score_w, score_b, basev);
    // 6) exp(dot+base) masked + per-b sums
    k_exp_sum<<<Bb * 4, 256, 0, stream>>>(dots, cand_len, basev, out, sumexp);
    // 7) normalize
    k_norm<<<256, 256, 0, stream>>>(out, sumexp);
}

// Round 5
// 366.324 us; speedup vs baseline: 1.0853x; 1.0853x over previous
//
#include <hip/hip_runtime.h>
#include <math.h>

// B=16 P=16 I=16 L=64 D=128 F=128 C=1024
#define Bb 16
#define Pp 16
#define Ii 16
#define Ll 64
#define Dd 128
#define Ff 128
#define Cc 1024

static __device__ __forceinline__ float dot4(float4 a, float4 b) {
    return a.x*b.x + a.y*b.y + a.z*b.z + a.w*b.w;
}

// async global->LDS, 16B per lane, wave-uniform LDS base + lane*16
#define GLOAD_LDS(gp, lp) __builtin_amdgcn_global_load_lds( \
    (const __attribute__((address_space(1))) void*)(gp),   \
    (__attribute__((address_space(3))) void*)(lp), 16, 0, 0)

// ---------------- Kernel 1: fused front end -------------------------------
// 8192 blocks: even blk = masked mean + conv (one bpi), odd blk = 64
// candidate dot scores. R5: all global reads go through
// __builtin_amdgcn_global_load_lds — the loads have no register dest, so
// the compiler cannot re-serialize them (R1-R3 showed it sinks any
// register-staged batch back to MLP=1; R4 showed fewer waves makes the
// latency-serial loop worse). Each wave queues its whole staging set
// back-to-back and drains once at vmcnt(0)+barrier.
__global__ __launch_bounds__(256) void k_front(
    const float* __restrict__ path_emb, const int* __restrict__ path_len,
    const float* __restrict__ conv_w, const float* __restrict__ conv_b,
    const float* __restrict__ cand_emb, const float* __restrict__ score_w,
    float* __restrict__ inst, float* __restrict__ dots,
    float* __restrict__ sumexp)
{
    __shared__ float4 buf[2048];          // 32 KB staging (64 rows x 512B)
    int blk = blockIdx.x;
    int t = threadIdx.x;
    int w = t >> 6;                       // wave 0..3
    int lane = t & 63;
    char* smem = (char*)buf;

    if ((blk & 1) == 0) {
        // ---- masked mean + conv: one block per bpi ----
        int bpi = blk >> 1;
        int len = path_len[bpi];
        const float4* gbase = (const float4*)(path_emb + (size_t)bpi * Ll * Dd);
        // stage rows [0, 2*ceil(len/2)) : each issue = 2 rows = 1 KB/wave
        for (int i = w; 2 * i < len; i += 4)
            GLOAD_LDS(gbase + i * 64 + lane, smem + i * 1024);
        asm volatile("s_waitcnt vmcnt(0)" ::: "memory");
        __syncthreads();

        // in-LDS masked sum: quad = t>>3 (0..31), g = t&7 row-group
        int quad = t >> 3, g = t & 7;
        float4 acc = make_float4(0.f, 0.f, 0.f, 0.f);
        for (int l = g; l < len; l += 8) {
            float4 v = buf[l * 32 + quad];
            acc.x += v.x; acc.y += v.y; acc.z += v.z; acc.w += v.w;
        }
        // combine the 8 row-groups (lanes differing in bits 0..2)
#pragma unroll
        for (int m = 1; m <= 4; m <<= 1) {
            acc.x += __shfl_xor(acc.x, m);
            acc.y += __shfl_xor(acc.y, m);
            acc.z += __shfl_xor(acc.z, m);
            acc.w += __shfl_xor(acc.w, m);
        }
        float inv = 1.0f / (float)len;
        acc.x *= inv; acc.y *= inv; acc.z *= inv; acc.w *= inv;
        __syncthreads();                  // all buf reads done
        if (g == 0) buf[quad] = acc;      // overlay mean onto buf[0..31]
        __syncthreads();

        // conv projection: threads 0..127 each compute one output f
        if (t < 128) {
            const float4* cw = (const float4*)(conv_w) + (size_t)t * 32;
            float a = conv_b[t];
#pragma unroll 8
            for (int dq = 0; dq < 32; ++dq) a += dot4(buf[dq], cw[dq]);
            inst[(size_t)bpi * Ff + t] = a;
        }
    } else {
        // ---- candidate dot scores: 64 candidates per block ----
        int idx = blk >> 1;               // 0..4095
        if (idx == 0 && t < Bb) sumexp[t] = 0.f;
        int bp = idx >> 4;                // 0..255
        int chunk = idx & 15;             // 0..15 (64 cands each)
        const float4* cbase = (const float4*)(cand_emb)
                            + ((size_t)bp * Cc + chunk * 64) * 32;
        // stage all 64 rows: 8 issues/wave, all in flight
        for (int i = w; i < 32; i += 4)
            GLOAD_LDS(cbase + i * 64 + lane, smem + i * 1024);
        asm volatile("s_waitcnt vmcnt(0)" ::: "memory");
        __syncthreads();

        int quad = t & 31, cl = t >> 5;   // 8 candidates concurrently
        float4 swq = ((const float4*)(score_w + 384))[quad];
#pragma unroll
        for (int it = 0; it < 8; ++it) {
            int c = cl + it * 8;          // 0..63
            float4 v = buf[c * 32 + quad];
            float p = dot4(v, swq);
            p += __shfl_xor(p, 16);
            p += __shfl_xor(p, 8);
            p += __shfl_xor(p, 4);
            p += __shfl_xor(p, 2);
            p += __shfl_xor(p, 1);
            if (quad == 0)
                dots[(size_t)bp * Cc + chunk * 64 + c] = p;
        }
    }
}

// ---------------- Generic tiled GEMM: C[M,N] = A[M,128] @ W[N,128]^T + b --
// Mtile=64, Ntile=96, 256 threads, micro-tile 4x6 per thread.
__global__ __launch_bounds__(256) void k_gemm(
    const float* __restrict__ A, const float* __restrict__ W,
    const float* __restrict__ bias, float* __restrict__ C,
    int N, int nbn)
{
    __shared__ float4 As[32 * 65];
    __shared__ float4 Wsh[32 * 97];
    int t = threadIdx.x;
    int bm = blockIdx.x / nbn, bn = blockIdx.x % nbn;

    {
        const float4* Ag = (const float4*)A + (size_t)(bm * 64) * 32;
        int k4 = t & 31;
        int m0 = (t >> 5) * 8;
#pragma unroll
        for (int r = 0; r < 8; ++r)
            As[k4 * 65 + m0 + r] = Ag[(size_t)(m0 + r) * 32 + k4];
    }
    {
        const float4* Wg = (const float4*)W + (size_t)(bn * 96) * 32;
        int k4 = t & 31;
        int n0 = (t >> 5) * 12;
#pragma unroll
        for (int r = 0; r < 12; ++r)
            Wsh[k4 * 97 + n0 + r] = Wg[(size_t)(n0 + r) * 32 + k4];
    }
    __syncthreads();

    int tn = t & 15;   // lane-fast over n -> coalesced C stores
    int tm = t >> 4;
    float acc[4][6];
#pragma unroll
    for (int i = 0; i < 4; ++i)
#pragma unroll
        for (int j = 0; j < 6; ++j) acc[i][j] = 0.f;

#pragma unroll 2
    for (int k4 = 0; k4 < 32; ++k4) {
        float4 a[4], b[6];
#pragma unroll
        for (int i = 0; i < 4; ++i) a[i] = As[k4 * 65 + tm + 16 * i];
#pragma unroll
        for (int j = 0; j < 6; ++j) b[j] = Wsh[k4 * 97 + tn + 16 * j];
#pragma unroll
        for (int i = 0; i < 4; ++i)
#pragma unroll
            for (int j = 0; j < 6; ++j)
                acc[i][j] += dot4(a[i], b[j]);
    }

#pragma unroll
    for (int i = 0; i < 4; ++i) {
        int m = bm * 64 + tm + 16 * i;
#pragma unroll
        for (int j = 0; j < 6; ++j) {
            int n = bn * 96 + tn + 16 * j;
            C[(size_t)m * N + n] = acc[i][j] + bias[n];
        }
    }
}

// ---------------- Kernel 2b: pia attention + mean + out proj -> meta -----
// grid = B*P = 256 blocks, 256 threads. out_w staged in LDS (f4-transposed).
__global__ __launch_bounds__(256) void k_pia_post(
    const float* __restrict__ qkv,
    const float* __restrict__ out_w, const float* __restrict__ out_b,
    float* __restrict__ meta)
{
    __shared__ float4 qs[16 * 33];
    __shared__ float4 ks[16 * 33];
    __shared__ float4 vs[16 * 33];
    __shared__ float4 ows[32 * 132];   // [k4][f] f4-transposed out_w
    __shared__ float Ss[16 * 17];
    __shared__ float wj[16];
    __shared__ float4 z4[32];
    int t = threadIdx.x, bp = blockIdx.x;
    float* vsf = (float*)vs;

    const float4* src = (const float4*)(qkv + (size_t)bp * 6144);
    for (int idx = t; idx < 1536; idx += 256) {
        int i = idx / 96, q = idx - i * 96;
        float4 v = src[idx];
        if (q < 32)       qs[i * 33 + q]        = v;
        else if (q < 64)  ks[i * 33 + (q - 32)] = v;
        else              vs[i * 33 + (q - 64)] = v;
    }
    {
        const float4* owg = (const float4*)out_w;
#pragma unroll
        for (int r = 0; r < 16; ++r) {
            int idx = t + 256 * r;
            int f = idx >> 5, k4 = idx & 31;
            ows[k4 * 132 + f] = owg[idx];
        }
    }
    __syncthreads();

    {
        int si = t >> 4, sj = t & 15;
        float s = 0.f;
#pragma unroll 8
        for (int dq = 0; dq < 32; ++dq)
            s += dot4(qs[si * 33 + dq], ks[sj * 33 + dq]);
        Ss[si * 17 + sj] = s * 0.08838834764831843f;
    }
    __syncthreads();
    if (t < 16) {
        float mx = -1e30f;
        for (int j = 0; j < 16; ++j) mx = fmaxf(mx, Ss[t * 17 + j]);
        float e[16]; float sum = 0.f;
        for (int j = 0; j < 16; ++j) { e[j] = expf(Ss[t * 17 + j] - mx); sum += e[j]; }
        float inv = 1.0f / sum;
        for (int j = 0; j < 16; ++j) Ss[t * 17 + j] = e[j] * inv;
    }
    __syncthreads();
    if (t < 16) {
        float s = 0.f;
        for (int i2 = 0; i2 < 16; ++i2) s += Ss[i2 * 17 + t];
        wj[t] = s * (1.0f / 16.0f);
    }
    __syncthreads();
    if (t < 128) {
        float s = 0.f;
#pragma unroll
        for (int j = 0; j < 16; ++j) s += wj[j] * vsf[j * 132 + t];
        ((float*)z4)[t] = s;
    }
    __syncthreads();
    if (t < 128) {
        float a = out_b[t];
#pragma unroll 8
        for (int k4 = 0; k4 < 32; ++k4) a += dot4(z4[k4], ows[k4 * 132 + t]);
        meta[(size_t)bp * Ff + t] = a;
    }
}

// ---------------- Kernel 3b: mpa attention + qia + base, per b ----------
__global__ __launch_bounds__(256) void k_mpa_post(
    const float* __restrict__ qkv, const float* __restrict__ meta,
    const float* __restrict__ query,
    const float* __restrict__ out_w, const float* __restrict__ out_b,
    const float* __restrict__ qia_in_w, const float* __restrict__ qia_in_b,
    const float* __restrict__ qia_out_w, const float* __restrict__ qia_out_b,
    const float* __restrict__ score_w, const float* __restrict__ score_b,
    float* __restrict__ basev)
{
    __shared__ float4 qs[16 * 33];
    __shared__ float4 ks[16 * 33];
    __shared__ float4 vs[16 * 33];
    __shared__ float Ss[16 * 17];
    __shared__ float wj[16];
    __shared__ float4 z4[32];
    __shared__ float4 mm4[32];
    __shared__ float v1s[128];
    __shared__ float4 tq4[32];
    __shared__ float v2s[128];
    __shared__ float red[128];
    int t = threadIdx.x, b = blockIdx.x;
    float* vsf = (float*)vs;

    const float4* src = (const float4*)(qkv + (size_t)b * 6144);
    for (int idx = t; idx < 1536; idx += 256) {
        int i = idx / 96, q = idx - i * 96;
        float4 v = src[idx];
        if (q < 32)       qs[i * 33 + q]        = v;
        else if (q < 64)  ks[i * 33 + (q - 32)] = v;
        else              vs[i * 33 + (q - 64)] = v;
    }
    float mmacc = 0.f;
    if (t < 128) {
#pragma unroll
        for (int p = 0; p < 16; ++p) mmacc += meta[(size_t)b * 2048 + p * 128 + t];
        mmacc *= (1.0f / 16.0f);
    }
    __syncthreads();

    {
        int si = t >> 4, sj = t & 15;
        float s = 0.f;
#pragma unroll 8
        for (int dq = 0; dq < 32; ++dq)
            s += dot4(qs[si * 33 + dq], ks[sj * 33 + dq]);
        Ss[si * 17 + sj] = s * 0.08838834764831843f;
    }
    if (t < 128) ((float*)mm4)[t] = mmacc;
    __syncthreads();
    if (t < 16) {
        float mx = -1e30f;
        for (int j = 0; j < 16; ++j) mx = fmaxf(mx, Ss[t * 17 + j]);
        float e[16]; float sum = 0.f;
        for (int j = 0; j < 16; ++j) { e[j] = expf(Ss[t * 17 + j] - mx); sum += e[j]; }
        float inv = 1.0f / sum;
        for (int j = 0; j < 16; ++j) Ss[t * 17 + j] = e[j] * inv;
    }
    __syncthreads();
    if (t < 16) {
        float s = 0.f;
        for (int i2 = 0; i2 < 16; ++i2) s += Ss[i2 * 17 + t];
        wj[t] = s * (1.0f / 16.0f);
    }
    __syncthreads();
    if (t < 128) {
        float s = 0.f;
#pragma unroll
        for (int j = 0; j < 16; ++j) s += wj[j] * vsf[j * 132 + t];
        ((float*)z4)[t] = s;
    }
    __syncthreads();

    if (t < 128) {
        const float4* w = (const float4*)(out_w) + (size_t)t * 32;
        float a = out_b[t];
#pragma unroll 8
        for (int dq = 0; dq < 32; ++dq) a += dot4(z4[dq], w[dq]);
        v1s[t] = a;
    } else {
        int f = t - 128;
        const float4* w = (const float4*)(qia_in_w) + (size_t)(256 + f) * 32;
        float a = qia_in_b[256 + f];
#pragma unroll 8
        for (int dq = 0; dq < 32; ++dq) a += dot4(mm4[dq], w[dq]);
        ((float*)tq4)[f] = a;
    }
    __syncthreads();
    if (t < 128) {
        const float4* w = (const float4*)(qia_out_w) + (size_t)t * 32;
        float a = qia_out_b[t];
#pragma unroll 8
        for (int dq = 0; dq < 32; ++dq) a += dot4(tq4[dq], w[dq]);
        v2s[t] = a;
    }
    __syncthreads();
    if (t < 128) {
        red[t] = query[(size_t)b * Dd + t] * score_w[t]
               + v1s[t] * score_w[128 + t]
               + v2s[t] * score_w[256 + t];
    }
    __syncthreads();
    for (int s = 64; s > 0; s >>= 1) {
        if (t < s) red[t] += red[t + s];
        __syncthreads();
    }
    if (t == 0) basev[b] = red[0] + score_b[0];
}

// ---------------- Kernel 4: exp(dot+base) with mask, per-b sum -----------
// grid = B*4 = 64 blocks, 256 threads; each block handles 4096 scores
// (4 consecutive p's of one b) as 1024 float4.
__global__ __launch_bounds__(256) void k_exp_sum(
    const float* __restrict__ dots, const int* __restrict__ cand_len,
    const float* __restrict__ basev, float* __restrict__ eout,
    float* __restrict__ sumexp)
{
    int blk = blockIdx.x;
    int b = blk >> 2, q = blk & 3;
    int t = threadIdx.x;
    float bb = basev[b];
    size_t off = (size_t)b * 16384 + (size_t)q * 4096;
    const float4* d4 = (const float4*)(dots + off);
    float4* o4 = (float4*)(eout + off);
    float lsum = 0.f;
#pragma unroll
    for (int r = 0; r < 4; ++r) {
        int idx4 = t + 256 * r;            // 0..1023
        int p = q * 4 + (idx4 >> 8);       // global p within b
        int c0 = (idx4 & 255) * 4;         // candidate index of .x
        int clen = cand_len[b * Pp + p];
        float4 v = d4[idx4];
        float4 e;
        e.x = (c0 + 0 < clen) ? expf(v.x + bb) : 0.f;
        e.y = (c0 + 1 < clen) ? expf(v.y + bb) : 0.f;
        e.z = (c0 + 2 < clen) ? expf(v.z + bb) : 0.f;
        e.w = (c0 + 3 < clen) ? expf(v.w + bb) : 0.f;
        o4[idx4] = e;
        lsum += e.x + e.y + e.z + e.w;
    }
    __shared__ float red[256];
    red[t] = lsum;
    __syncthreads();
    for (int s = 128; s > 0; s >>= 1) {
        if (t < s) red[t] += red[t + s];
        __syncthreads();
    }
    if (t == 0) atomicAdd(&sumexp[b], red[0]);
}

// ---------------- Kernel 5: normalize ------------------------------------
__global__ __launch_bounds__(256) void k_norm(
    float* __restrict__ out, const float* __restrict__ sumexp)
{
    int idx = blockIdx.x * 256 + threadIdx.x;
    int b = idx >> 12;  // 4096 float4 per batch
    float inv = 1.0f / sumexp[b];
    float4* o4 = (float4*)out;
    float4 v = o4[idx];
    v.x *= inv; v.y *= inv; v.z *= inv; v.w *= inv;
    o4[idx] = v;
}

extern "C" void kernel_launch(void* const* d_in, const int* in_sizes, int n_in,
                              void* d_out, int out_size, void* d_ws, size_t ws_size,
                              hipStream_t stream)
{
    const float* query    = (const float*)d_in[0];
    const float* path_emb = (const float*)d_in[1];
    const int*   path_len = (const int*)  d_in[2];
    const float* cand_emb = (const float*)d_in[3];
    const int*   cand_len = (const int*)  d_in[4];
    const float* conv_w   = (const float*)d_in[5];
    const float* conv_b   = (const float*)d_in[6];
    const float* pia_in_w = (const float*)d_in[7];
    const float* pia_in_b = (const float*)d_in[8];
    const float* pia_out_w= (const float*)d_in[9];
    const float* pia_out_b= (const float*)d_in[10];
    const float* mpa_in_w = (const float*)d_in[11];
    const float* mpa_in_b = (const float*)d_in[12];
    const float* mpa_out_w= (const float*)d_in[13];
    const float* mpa_out_b= (const float*)d_in[14];
    const float* qia_in_w = (const float*)d_in[15];
    const float* qia_in_b = (const float*)d_in[16];
    const float* qia_out_w= (const float*)d_in[17];
    const float* qia_out_b= (const float*)d_in[18];
    const float* score_w  = (const float*)d_in[19];
    const float* score_b  = (const float*)d_in[20];
    float* out = (float*)d_out;

    float* ws      = (float*)d_ws;
    float* inst    = ws;                        // B*P*I*F = 524288 floats
    float* meta    = ws + 524288;               // B*P*F   = 32768
    float* basev   = ws + 524288 + 32768;       // 16
    float* sumexp  = basev + 16;                // 16
    float* qkv_pia = sumexp + 16;               // 4096*384 = 1572864
    float* qkv_mpa = qkv_pia + 1572864;         // 256*384  = 98304
    float* dots    = qkv_mpa + 98304;           // B*P*C    = 262144

    // 1) fused: masked-mean+conv (even blocks) + cand dots (odd blocks),
    //    all global reads via async global_load_lds staging
    k_front<<<8192, 256, 0, stream>>>(path_emb, path_len, conv_w, conv_b,
                                      cand_emb, score_w,
                                      inst, dots, sumexp);
    // 2) pia qkv: M=4096, N=384 -> 64 x 4 = 256 blocks
    k_gemm<<<64 * 4, 256, 0, stream>>>(inst, pia_in_w, pia_in_b, qkv_pia, 384, 4);
    // 3) pia attention + mean + out-proj
    k_pia_post<<<Bb * Pp, 256, 0, stream>>>(qkv_pia, pia_out_w, pia_out_b, meta);
    // 4) mpa qkv: M=256, N=384 -> 4 x 4 = 16 blocks
    k_gemm<<<4 * 4, 256, 0, stream>>>(meta, mpa_in_w, mpa_in_b, qkv_mpa, 384, 4);
    // 5) mpa attention + qia + per-b base scalar
    k_mpa_post<<<Bb, 256, 0, stream>>>(qkv_mpa, meta, query,
                                       mpa_out_w, mpa_out_b,
                                       qia_in_w, qia_in_b, qia_out_w, qia_out_b,
                                       score_w, score_b, basev);
    // 6) exp(dot+base) masked + per-b sums
    k_exp_sum<<<Bb * 4, 256, 0, stream>>>(dots, cand_len, basev, out, sumexp);
    // 7) normalize
    k_norm<<<256, 256, 0, stream>>>(out, sumexp);
}

// Round 6
// 280.676 us; speedup vs baseline: 1.4165x; 1.3052x over previous
//
#include <hip/hip_runtime.h>
#include <math.h>

// B=16 P=16 I=16 L=64 D=128 F=128 C=1024
#define Bb 16
#define Pp 16
#define Cc 1024

static __device__ __forceinline__ float dot4(float4 a, float4 b) {
    return a.x*b.x + a.y*b.y + a.z*b.z + a.w*b.w;
}

// ---------------------------------------------------------------------------
// R6 key algebraic fact: scores[b,p,c] = K(b) + cand_emb[b,p,c,:]·score_w[384:512]
// where K(b) collects the query/v1/v2/score_b terms (all per-b broadcasts —
// v1, v2 are means over p and depend only on b). The final softmax is over
// the flattened (p*c) axis per b, and softmax(x + K) == softmax(x), so the
// entire path_emb -> conv -> pia -> mpa -> qia -> base chain cancels out of
// the output. Masked entries are 0 either way (exp(-1e9-max) == 0 in f32).
// Only cand_emb (134 MB, L3-resident once path_emb is no longer streamed),
// cand_len and score_w[384:512] matter.
// ---------------------------------------------------------------------------

// Kernel A: masked exp(cand dot) + per-block partial sums.
// grid = 2048: bp (0..255) x chunk (0..7), 128 candidates per block.
// Coalescing: quad = t&31 spans one 512B row across 32 lanes (16B each);
// a wave covers 2 adjacent rows = 1 KB contiguous per load instruction.
__global__ __launch_bounds__(256) void k_dots_exp(
    const float* __restrict__ cand_emb, const int* __restrict__ cand_len,
    const float* __restrict__ score_w,
    float* __restrict__ out, float* __restrict__ partials)
{
    int blk = blockIdx.x;              // 0..2047
    int bp = blk >> 3;                 // 0..255  (b*16+p)
    int chunk = blk & 7;               // 0..7 -> candidates [chunk*128, +128)
    int t = threadIdx.x;
    int quad = t & 31;                 // float4 column within the 128-dim row
    int cl = t >> 5;                   // 8 candidates processed concurrently
    int clen = cand_len[bp];
    float4 swq = ((const float4*)(score_w + 384))[quad];
    const float4* cbase = (const float4*)(cand_emb)
                        + ((size_t)bp * Cc + chunk * 128) * 32;

    __shared__ float ps[8];
    float lsum = 0.f;
#pragma unroll 4
    for (int it = 0; it < 16; ++it) {
        int c = cl + it * 8;           // local candidate 0..127
        float4 v = cbase[(size_t)c * 32 + quad];
        float p = dot4(v, swq);
        p += __shfl_xor(p, 16);
        p += __shfl_xor(p, 8);
        p += __shfl_xor(p, 4);
        p += __shfl_xor(p, 2);
        p += __shfl_xor(p, 1);
        int cg = chunk * 128 + c;      // global candidate 0..1023
        float e = (cg < clen) ? expf(p) : 0.f;
        if (quad == 0) {
            out[(size_t)bp * Cc + cg] = e;
            lsum += e;
        }
    }
    if (quad == 0) ps[cl] = lsum;      // 8 group sums (t = 0,32,...,224)
    __syncthreads();
    if (t == 0) {
        float s = 0.f;
#pragma unroll
        for (int i = 0; i < 8; ++i) s += ps[i];
        partials[blk] = s;             // indexed (b*16+p)*8+chunk -> b-major
    }
}

// Kernel B: normalize. 256 blocks x 256 threads x float4 = 262144 floats.
// Each block re-reduces its batch's 128 partials (128 L2-hit loads, trivial)
// -> no atomics, no zero-init kernel, deterministic.
__global__ __launch_bounds__(256) void k_norm(
    float* __restrict__ out, const float* __restrict__ partials)
{
    __shared__ float red[128];
    int blk = blockIdx.x;
    int t = threadIdx.x;
    int b = blk >> 4;                  // 16 blocks per batch
    if (t < 128) red[t] = partials[b * 128 + t];
    __syncthreads();
    for (int s = 64; s > 0; s >>= 1) {
        if (t < s) red[t] += red[t + s];
        __syncthreads();
    }
    float inv = 1.0f / red[0];
    int idx = blk * 256 + t;
    float4* o4 = (float4*)out;
    float4 v = o4[idx];
    v.x *= inv; v.y *= inv; v.z *= inv; v.w *= inv;
    o4[idx] = v;
}

extern "C" void kernel_launch(void* const* d_in, const int* in_sizes, int n_in,
                              void* d_out, int out_size, void* d_ws, size_t ws_size,
                              hipStream_t stream)
{
    const float* cand_emb = (const float*)d_in[3];
    const int*   cand_len = (const int*)  d_in[4];
    const float* score_w  = (const float*)d_in[19];
    float* out = (float*)d_out;

    float* partials = (float*)d_ws;    // 2048 floats

    // 1) masked exp(dot) + per-block partial sums
    k_dots_exp<<<2048, 256, 0, stream>>>(cand_emb, cand_len, score_w,
                                         out, partials);
    // 2) per-b reduce + normalize
    k_norm<<<256, 256, 0, stream>>>(out, partials);
}